// Round 5
// baseline (284.673 us; speedup 1.0000x reference)
//
#include <hip/hip_runtime.h>

#define SEQ  20
#define DK   64
#define SSTR 24     // score row stride in floats (96 B, float4-aligned)

// ---------------- Kernel 1: attn = (exp(QK^T * scale) * mask) / rowsum ------
// One block = one (b,h). 200 threads compute 2 scores each (1q x 2k); Q/K rows
// are read straight from global (10 KB working set -> L1-resident, 10-20x
// reuse). Only the 20x20 score matrix lives in LDS.
__global__ __launch_bounds__(256)
void k1_scores(const float* __restrict__ Qg,
               const float* __restrict__ Kg,
               const float* __restrict__ Mg,
               float* __restrict__ attnOut)
{
    __shared__ float sS[SEQ * SSTR];
    __shared__ float sRinv[SEQ];

    const int bh = blockIdx.x;
    const int t  = threadIdx.x;
    const size_t base = (size_t)bh * (SEQ * DK);
    const float4* gq = reinterpret_cast<const float4*>(Qg + base);
    const float4* gk = reinterpret_cast<const float4*>(Kg + base);

    if (t < 200) {
        const int q  = t / 10;
        const int k0 = 2 * (t - 10 * q);
        float a0 = 0.f, a1 = 0.f;
        #pragma unroll 4                 // 12 independent loads in flight
        for (int g = 0; g < 16; ++g) {
            const float4 qv = gq[q * 16 + g];
            const float4 ka = gk[(k0    ) * 16 + g];
            const float4 kb = gk[(k0 + 1) * 16 + g];
            a0 = fmaf(qv.x, ka.x, a0); a0 = fmaf(qv.y, ka.y, a0);
            a0 = fmaf(qv.z, ka.z, a0); a0 = fmaf(qv.w, ka.w, a0);
            a1 = fmaf(qv.x, kb.x, a1); a1 = fmaf(qv.y, kb.y, a1);
            a1 = fmaf(qv.z, kb.z, a1); a1 = fmaf(qv.w, kb.w, a1);
        }
        const float2 mm = *reinterpret_cast<const float2*>(
            Mg + (size_t)bh * (SEQ * SEQ) + q * SEQ + k0);
        float2 e;
        e.x = __expf(a0 * 0.125f) * mm.x;
        e.y = __expf(a1 * 0.125f) * mm.y;
        *reinterpret_cast<float2*>(sS + q * SSTR + k0) = e;
    }
    __syncthreads();

    if (t < SEQ) {
        float s = 0.f;
        #pragma unroll
        for (int k = 0; k < SEQ; ++k) s += sS[t * SSTR + k];
        sRinv[t] = 1.0f / (s + 1e-8f);
    }
    __syncthreads();

    if (t < 100) {
        const int q  = t / 5;
        const int g4 = (t - 5 * q) * 4;
        const float4 sv = *reinterpret_cast<const float4*>(sS + q * SSTR + g4);
        const float r = sRinv[q];
        *reinterpret_cast<float4*>(attnOut + (size_t)bh * (SEQ * SEQ) + q * SEQ + g4) =
            make_float4(sv.x * r, sv.y * r, sv.z * r, sv.w * r);
    }
}

// ---------------- Kernel 2: deAtt = (attn + Md) @ V ------------------------
// One block = one (b,h), 320 threads = exactly one float4 output each.
// No LDS, no barriers, no divergence. Per thread: 5 attn-f4 + 20 V-f4 loads,
// all independent (two 10-deep batches), one coalesced f4 store.
__global__ __launch_bounds__(320)
void k2_pv(const float* __restrict__ attn,
           const float* __restrict__ Vg,
           float* __restrict__ deAtt)
{
    const int bh = blockIdx.x;
    const int t  = threadIdx.x;
    const int q  = t >> 4;      // 0..19
    const int dg = t & 15;      // float4 column group 0..15

    const size_t base = (size_t)bh * (SEQ * DK);
    const float4* gv   = reinterpret_cast<const float4*>(Vg + base);
    const float4* arow = reinterpret_cast<const float4*>(
        attn + (size_t)bh * (SEQ * SEQ) + q * SEQ);

    // attn row -> 20 scalar registers (all indices compile-time constant)
    float a[SEQ];
    #pragma unroll
    for (int i = 0; i < 5; ++i) {
        const float4 x = arow[i];
        a[4 * i + 0] = x.x; a[4 * i + 1] = x.y;
        a[4 * i + 2] = x.z; a[4 * i + 3] = x.w;
    }

    const float qf = (float)q;
    float4 acc = make_float4(0.f, 0.f, 0.f, 0.f);

    #pragma unroll
    for (int h = 0; h < 2; ++h) {
        float4 v[10];
        #pragma unroll
        for (int k = 0; k < 10; ++k)
            v[k] = gv[(h * 10 + k) * 16 + dg];   // 10 independent loads in flight
        #pragma unroll
        for (int k = 0; k < 10; ++k) {
            const int kk = h * 10 + k;
            const float w = a[kk] - fabsf(qf - (float)kk);   // attn + Md folded
            acc.x = fmaf(w, v[k].x, acc.x);
            acc.y = fmaf(w, v[k].y, acc.y);
            acc.z = fmaf(w, v[k].z, acc.z);
            acc.w = fmaf(w, v[k].w, acc.w);
        }
    }

    reinterpret_cast<float4*>(deAtt + base + q * DK)[dg] = acc;
}

extern "C" void kernel_launch(void* const* d_in, const int* in_sizes, int n_in,
                              void* d_out, int out_size, void* d_ws, size_t ws_size,
                              hipStream_t stream) {
    const float* Q = (const float*)d_in[0];
    const float* K = (const float*)d_in[1];
    const float* V = (const float*)d_in[2];
    const float* M = (const float*)d_in[3];
    float* out = (float*)d_out;

    const int nbh = in_sizes[0] / (SEQ * DK);        // B*H = 8192
    float* deAtt = out;                              // [nbh, SEQ, DK]
    float* attn  = out + (size_t)nbh * SEQ * DK;     // [nbh, SEQ, SEQ]

    k1_scores<<<nbh, 256, 0, stream>>>(Q, K, M, attn);
    k2_pv<<<nbh, 320, 0, stream>>>(attn, V, deAtt);
}

// Round 6
// 220.743 us; speedup vs baseline: 1.2896x; 1.2896x over previous
//
#include <hip/hip_runtime.h>

#define SEQ   20
#define DK    64
#define NG    16          // float4 groups per 64-float row
#define SSTR  24          // score row stride in floats (96 B, f4-aligned)
#define BHPB  4           // bh per block
#define NT    320         // threads per block (5 waves)

// Per bh handled by one block (4 bh/block):
//   Phase A: stage V (coalesced, 4 f4/thread)        -- LDS write, no barrier dep
//   Phase B: scores = exp(QK^T/8)*mask, 2q x 4k reg tiles, Q/K from global/L1
//   barrier
//   Phase C: row sums -> rinv (80 lanes)
//   barrier
//   Phase D: attn out = s * rinv (400 f4 units)
//   Phase E: deAtt = (attn + Md) @ V, V from LDS (4q x f4col units, 320 lanes)
__global__ __launch_bounds__(NT, 8)   // cap VGPR at 64 => 8 waves/EU possible
void fused_deatt_v6(const float* __restrict__ Qg,
                    const float* __restrict__ Kg,
                    const float* __restrict__ Vg,
                    const float* __restrict__ Mg,
                    float* __restrict__ deAtt,
                    float* __restrict__ attnOut)
{
    __shared__ float4 sV[BHPB * SEQ * NG];          // 20 KB
    __shared__ float  sS[BHPB * SEQ * SSTR];        // 7.5 KB
    __shared__ float  sRinv[BHPB * SEQ];            // 320 B

    const int t   = threadIdx.x;
    const int bh0 = blockIdx.x * BHPB;              // nbh divisible by 4 (8192)

    // ---------------- Phase A: stage V (coalesced) ----------------
    {
        const float4* gv = reinterpret_cast<const float4*>(Vg) + (size_t)bh0 * (SEQ * NG);
        #pragma unroll
        for (int j = 0; j < BHPB; ++j)
            sV[j * (SEQ * NG) + t] = gv[j * (SEQ * NG) + t];
    }

    // ---------------- Phase B: scores; 2q x 4k tiles; lanes 0..199 ----------------
    if (t < 200) {
        const int bl   = t / 50;                 // local bh 0..3
        const int tile = t - bl * 50;            // 0..49
        const int qt   = tile / 5;               // 0..9 -> q0 = 2qt
        const int kt   = tile - qt * 5;          // 0..4 -> k0 = 4kt
        const int q0   = qt * 2, k0 = kt * 4;
        const int bh   = bh0 + bl;

        const float4* gq = reinterpret_cast<const float4*>(Qg) + (size_t)bh * (SEQ * NG);
        const float4* gk = reinterpret_cast<const float4*>(Kg) + (size_t)bh * (SEQ * NG);

        float a00=0.f,a01=0.f,a02=0.f,a03=0.f;
        float a10=0.f,a11=0.f,a12=0.f,a13=0.f;
        #pragma unroll 2                          // ~12 independent loads in flight
        for (int g = 0; g < NG; ++g) {
            const float4 qa = gq[(q0    ) * NG + g];
            const float4 qb = gq[(q0 + 1) * NG + g];
            const float4 k0v = gk[(k0 + 0) * NG + g];
            const float4 k1v = gk[(k0 + 1) * NG + g];
            const float4 k2v = gk[(k0 + 2) * NG + g];
            const float4 k3v = gk[(k0 + 3) * NG + g];
            a00 = fmaf(qa.x,k0v.x,a00); a00 = fmaf(qa.y,k0v.y,a00); a00 = fmaf(qa.z,k0v.z,a00); a00 = fmaf(qa.w,k0v.w,a00);
            a01 = fmaf(qa.x,k1v.x,a01); a01 = fmaf(qa.y,k1v.y,a01); a01 = fmaf(qa.z,k1v.z,a01); a01 = fmaf(qa.w,k1v.w,a01);
            a02 = fmaf(qa.x,k2v.x,a02); a02 = fmaf(qa.y,k2v.y,a02); a02 = fmaf(qa.z,k2v.z,a02); a02 = fmaf(qa.w,k2v.w,a02);
            a03 = fmaf(qa.x,k3v.x,a03); a03 = fmaf(qa.y,k3v.y,a03); a03 = fmaf(qa.z,k3v.z,a03); a03 = fmaf(qa.w,k3v.w,a03);
            a10 = fmaf(qb.x,k0v.x,a10); a10 = fmaf(qb.y,k0v.y,a10); a10 = fmaf(qb.z,k0v.z,a10); a10 = fmaf(qb.w,k0v.w,a10);
            a11 = fmaf(qb.x,k1v.x,a11); a11 = fmaf(qb.y,k1v.y,a11); a11 = fmaf(qb.z,k1v.z,a11); a11 = fmaf(qb.w,k1v.w,a11);
            a12 = fmaf(qb.x,k2v.x,a12); a12 = fmaf(qb.y,k2v.y,a12); a12 = fmaf(qb.z,k2v.z,a12); a12 = fmaf(qb.w,k2v.w,a12);
            a13 = fmaf(qb.x,k3v.x,a13); a13 = fmaf(qb.y,k3v.y,a13); a13 = fmaf(qb.z,k3v.z,a13); a13 = fmaf(qb.w,k3v.w,a13);
        }
        const float* m = Mg + (size_t)bh * (SEQ * SEQ);
        const float4 m0 = *reinterpret_cast<const float4*>(m + (q0    ) * SEQ + k0);
        const float4 m1 = *reinterpret_cast<const float4*>(m + (q0 + 1) * SEQ + k0);
        float* s0 = sS + (bl * SEQ + q0) * SSTR + k0;
        float* s1 = s0 + SSTR;
        *reinterpret_cast<float4*>(s0) = make_float4(
            __expf(a00 * 0.125f) * m0.x, __expf(a01 * 0.125f) * m0.y,
            __expf(a02 * 0.125f) * m0.z, __expf(a03 * 0.125f) * m0.w);
        *reinterpret_cast<float4*>(s1) = make_float4(
            __expf(a10 * 0.125f) * m1.x, __expf(a11 * 0.125f) * m1.y,
            __expf(a12 * 0.125f) * m1.z, __expf(a13 * 0.125f) * m1.w);
    }
    __syncthreads();

    // ---------------- Phase C: row sums -> rinv; lanes 0..79 ----------------
    if (t < BHPB * SEQ) {
        const float4* row = reinterpret_cast<const float4*>(sS + t * SSTR);
        const float4 r0 = row[0], r1 = row[1], r2 = row[2], r3 = row[3], r4 = row[4];
        const float s = r0.x + r0.y + r0.z + r0.w
                      + r1.x + r1.y + r1.z + r1.w
                      + r2.x + r2.y + r2.z + r2.w
                      + r3.x + r3.y + r3.z + r3.w
                      + r4.x + r4.y + r4.z + r4.w;
        sRinv[t] = 1.0f / (s + 1e-8f);
    }
    __syncthreads();

    // ---------------- Phase D: write attn (400 f4 units) ----------------
    {
        #pragma unroll
        for (int r = 0; r < 2; ++r) {
            const int u = t + r * NT;
            if (u < BHPB * 100) {
                const int bl = u / 100;
                const int rm = u - bl * 100;
                const int q  = rm / 5;
                const int g4 = (rm - q * 5) * 4;
                const float4 sv = *reinterpret_cast<const float4*>(
                    sS + (bl * SEQ + q) * SSTR + g4);
                const float rv = sRinv[bl * SEQ + q];
                *reinterpret_cast<float4*>(
                    attnOut + (size_t)(bh0 + bl) * (SEQ * SEQ) + q * SEQ + g4) =
                    make_float4(sv.x * rv, sv.y * rv, sv.z * rv, sv.w * rv);
            }
        }
    }

    // ---------------- Phase E: deAtt = (attn + Md) @ V; 320 units ----------------
    {
        const int bl = t / 80;                   // local bh
        const int u  = t - bl * 80;              // 0..79
        const int qg = u / 16;                   // 0..4 -> q rows 4qg..4qg+3
        const int dg = u - qg * 16;              // f4 column 0..15
        const int q0 = qg * 4;

        const float4* vb = sV + bl * (SEQ * NG);
        const float*  sb = sS + bl * SEQ * SSTR;
        const float rv0 = sRinv[bl * SEQ + q0 + 0];
        const float rv1 = sRinv[bl * SEQ + q0 + 1];
        const float rv2 = sRinv[bl * SEQ + q0 + 2];
        const float rv3 = sRinv[bl * SEQ + q0 + 3];

        float4 acc0 = make_float4(0.f,0.f,0.f,0.f);
        float4 acc1 = make_float4(0.f,0.f,0.f,0.f);
        float4 acc2 = make_float4(0.f,0.f,0.f,0.f);
        float4 acc3 = make_float4(0.f,0.f,0.f,0.f);

        #pragma unroll
        for (int k4 = 0; k4 < 5; ++k4) {
            const int kb = k4 * 4;
            const float4 v0 = vb[(kb + 0) * NG + dg];
            const float4 v1 = vb[(kb + 1) * NG + dg];
            const float4 v2 = vb[(kb + 2) * NG + dg];
            const float4 v3 = vb[(kb + 3) * NG + dg];
            const float4 s0 = *reinterpret_cast<const float4*>(sb + (q0 + 0) * SSTR + kb);
            const float4 s1 = *reinterpret_cast<const float4*>(sb + (q0 + 1) * SSTR + kb);
            const float4 s2 = *reinterpret_cast<const float4*>(sb + (q0 + 2) * SSTR + kb);
            const float4 s3 = *reinterpret_cast<const float4*>(sb + (q0 + 3) * SSTR + kb);
            const float kf0 = (float)(kb + 0), kf1 = (float)(kb + 1);
            const float kf2 = (float)(kb + 2), kf3 = (float)(kb + 3);

            #define EROW(ACC, SV, RV, QF)                                          \
            {                                                                       \
                const float w0 = fmaf(SV.x, RV, -fabsf(QF - kf0));                  \
                const float w1 = fmaf(SV.y, RV, -fabsf(QF - kf1));                  \
                const float w2 = fmaf(SV.z, RV, -fabsf(QF - kf2));                  \
                const float w3 = fmaf(SV.w, RV, -fabsf(QF - kf3));                  \
                ACC.x = fmaf(w0, v0.x, ACC.x); ACC.x = fmaf(w1, v1.x, ACC.x);       \
                ACC.x = fmaf(w2, v2.x, ACC.x); ACC.x = fmaf(w3, v3.x, ACC.x);       \
                ACC.y = fmaf(w0, v0.y, ACC.y); ACC.y = fmaf(w1, v1.y, ACC.y);       \
                ACC.y = fmaf(w2, v2.y, ACC.y); ACC.y = fmaf(w3, v3.y, ACC.y);       \
                ACC.z = fmaf(w0, v0.z, ACC.z); ACC.z = fmaf(w1, v1.z, ACC.z);       \
                ACC.z = fmaf(w2, v2.z, ACC.z); ACC.z = fmaf(w3, v3.z, ACC.z);       \
                ACC.w = fmaf(w0, v0.w, ACC.w); ACC.w = fmaf(w1, v1.w, ACC.w);       \
                ACC.w = fmaf(w2, v2.w, ACC.w); ACC.w = fmaf(w3, v3.w, ACC.w);       \
            }
            EROW(acc0, s0, rv0, (float)(q0 + 0))
            EROW(acc1, s1, rv1, (float)(q0 + 1))
            EROW(acc2, s2, rv2, (float)(q0 + 2))
            EROW(acc3, s3, rv3, (float)(q0 + 3))
            #undef EROW
        }

        float4* outp = reinterpret_cast<float4*>(deAtt + (size_t)(bh0 + bl) * (SEQ * DK));
        outp[(q0 + 0) * NG + dg] = acc0;
        outp[(q0 + 1) * NG + dg] = acc1;
        outp[(q0 + 2) * NG + dg] = acc2;
        outp[(q0 + 3) * NG + dg] = acc3;
    }
}

extern "C" void kernel_launch(void* const* d_in, const int* in_sizes, int n_in,
                              void* d_out, int out_size, void* d_ws, size_t ws_size,
                              hipStream_t stream) {
    const float* Q = (const float*)d_in[0];
    const float* K = (const float*)d_in[1];
    const float* V = (const float*)d_in[2];
    const float* M = (const float*)d_in[3];
    float* out = (float*)d_out;

    const int nbh = in_sizes[0] / (SEQ * DK);        // B*H = 8192 (divisible by 4)
    float* deAtt = out;                              // [nbh, SEQ, DK]
    float* attn  = out + (size_t)nbh * SEQ * DK;     // [nbh, SEQ, SEQ]

    fused_deatt_v6<<<nbh / BHPB, NT, 0, stream>>>(Q, K, V, M, deAtt, attn);
}